// Round 9
// baseline (334.114 us; speedup 1.0000x reference)
//
#include <hip/hip_runtime.h>

#define N_NODES 100000
#define N_EDGES 800000
#define NF 81
#define NB 22
#define OC 64
#define SCAN_CHUNK 1024
#define SCAN_BLOCKS ((N_NODES + SCAN_CHUNK - 1) / SCAN_CHUNK)   // 98

typedef __attribute__((ext_vector_type(8))) short bf16x8;
typedef __attribute__((ext_vector_type(4))) float f32x4;

#if defined(__has_builtin)
#if __has_builtin(__builtin_amdgcn_fdot2_f32_bf16)
#define HAVE_FDOT2 1
#endif
#endif

#ifdef HAVE_FDOT2
typedef __attribute__((ext_vector_type(2))) __bf16 bfv2;
#endif

// dot2: c += lo(a)*lo(b) + hi(a)*hi(b), operands are packed bf16 pairs
__device__ inline float dot2b(unsigned a, unsigned b, float c) {
#ifdef HAVE_FDOT2
    return __builtin_amdgcn_fdot2_f32_bf16(__builtin_bit_cast(bfv2, a),
                                           __builtin_bit_cast(bfv2, b), c, false);
#else
    return c + __uint_as_float(a << 16)         * __uint_as_float(b << 16)
             + __uint_as_float(a & 0xffff0000u) * __uint_as_float(b & 0xffff0000u);
#endif
}

// round-to-nearest-even fp32 -> bf16 (high part), returns residual in rest
__device__ inline unsigned short bfsplit(float v, float& rest) {
    const unsigned b = __float_as_uint(v);
    const unsigned short h = (unsigned short)((b + 0x7fffu + ((b >> 16) & 1u)) >> 16);
    rest = v - __uint_as_float(((unsigned)h) << 16);
    return h;
}

__device__ inline unsigned pk_bf16(float a, float b) {
    const unsigned ua = (__float_as_uint(a) + 0x8000u) >> 16;
    const unsigned ub = (__float_as_uint(b) + 0x8000u) & 0xffff0000u;
    return ua | ub;
}

// defensive index clamp (keeps any corrupt perm value in-bounds)
__device__ inline int clampe(int p) {
    return ((unsigned)p < (unsigned)N_EDGES) ? p : 0;
}

// ---------------------------------------------------------------------------
// Build B^T in bf16 hi/lo: BT[c][k], c in [0,128), k in [0,96).
// DEDICATED workspace region (no aliasing with edge records).
__global__ void k_wprep(const float* __restrict__ w_s, const float* __restrict__ w_n,
                        short* __restrict__ bt)
{
    const int tid = blockIdx.x * blockDim.x + threadIdx.x;
    if (tid >= 128 * 96) return;
    const int c = tid / 96;
    const int k = tid - c * 96;
    float v = 0.f;
    if (k < NF) v = (c < OC) ? w_s[k * OC + c] : w_n[k * OC + (c - OC)];
    float rest, dummy;
    const unsigned short h = bfsplit(v, rest);
    const unsigned short l = bfsplit(rest, dummy);
    bt[c * 96 + k]               = (short)h;          // BT_hi
    bt[128 * 96 + c * 96 + k]    = (short)l;          // BT_lo
}

// ---------------------------------------------------------------------------
// Node GEMM on matrix cores: [out | pb] = feat @ [w_s | w_n[:81]]
// Split-bf16 3-pass MFMA (Ah*Bh + Ah*Bl + Al*Bh) -> ~2^-17 relative error.
__global__ __launch_bounds__(256) void k_node_mfma(
    const float* __restrict__ feat, const short* __restrict__ bt,
    float* __restrict__ out, float* __restrict__ pb, float4* __restrict__ xyz)
{
    __shared__ short shA[2 * 64 * 104];               // hi at 0, lo at 6656 (26.6 KB)
    const int t    = threadIdx.x;
    const int lane = t & 63;
    const int w    = t >> 6;
    const int n0   = blockIdx.x * 64;

    // ---- B fragments from global B^T (L2-resident, 16B-aligned b128 loads)
    const int krow = (lane >> 4) * 8;                 // k offset within 32-k tile
    bf16x8 Bh[3][2], Bl[3][2];
#pragma unroll
    for (int kt = 0; kt < 3; ++kt)
#pragma unroll
        for (int c = 0; c < 2; ++c) {
            const int col = w * 32 + c * 16 + (lane & 15);
            const int off = col * 96 + kt * 32 + krow;
            Bh[kt][c] = *(const bf16x8*)(bt + off);
            Bl[kt][c] = *(const bf16x8*)(bt + 128 * 96 + off);
        }

    // ---- stage A (64 rows x 81 k) as bf16 hi/lo into LDS
    const long gbase = (long)n0 * NF;
    const long gmax  = (long)N_NODES * NF;
    for (int j = t; j < (64 * NF) / 4; j += 256) {    // 1296 float4s
        const int flat = j * 4;
        float v[4];
        if (gbase + flat + 3 < gmax) {
            const float4 q = *(const float4*)(feat + gbase + flat);
            v[0] = q.x; v[1] = q.y; v[2] = q.z; v[3] = q.w;
        } else {
#pragma unroll
            for (int i = 0; i < 4; ++i)
                v[i] = (gbase + flat + i < gmax) ? feat[gbase + flat + i] : 0.f;
        }
#pragma unroll
        for (int i = 0; i < 4; ++i) {
            const int fi  = flat + i;
            const int row = (int)((unsigned)fi / 81u);
            const int k   = fi - row * 81;
            float rest, dummy;
            const unsigned short h = bfsplit(v[i], rest);
            const unsigned short l = bfsplit(rest, dummy);
            shA[row * 104 + k]        = (short)h;
            shA[6656 + row * 104 + k] = (short)l;
        }
    }
    // zero K padding 81..96 (frags read up to k=95)
    for (int j = t; j < 64 * 16; j += 256) {
        const int row = j >> 4, k = NF + (j & 15);
        shA[row * 104 + k] = 0;
        shA[6656 + row * 104 + k] = 0;
    }

    // xyz in exact fp32 (distance path must stay fp32-accurate)
    if (t < 64 && n0 + t < N_NODES) {
        const float* fp = feat + (long)(n0 + t) * NF;
        xyz[n0 + t] = make_float4(fp[0], fp[1], fp[2], 0.f);
    }
    __syncthreads();

    // ---- MFMA: 4 row-tiles x 2 col-tiles x 3 k-tiles x 3 passes
    f32x4 acc[4][2];
#pragma unroll
    for (int rt = 0; rt < 4; ++rt)
#pragma unroll
        for (int c = 0; c < 2; ++c)
            acc[rt][c] = (f32x4){0.f, 0.f, 0.f, 0.f};

#pragma unroll
    for (int kt = 0; kt < 3; ++kt) {
        bf16x8 Ah[4], Al[4];
#pragma unroll
        for (int rt = 0; rt < 4; ++rt) {
            const int o = (rt * 16 + (lane & 15)) * 104 + kt * 32 + krow;
            Ah[rt] = *(const bf16x8*)(shA + o);
            Al[rt] = *(const bf16x8*)(shA + 6656 + o);
        }
#pragma unroll
        for (int rt = 0; rt < 4; ++rt)
#pragma unroll
            for (int c = 0; c < 2; ++c) {
                f32x4 a = acc[rt][c];
                a = __builtin_amdgcn_mfma_f32_16x16x32_bf16(Ah[rt], Bh[kt][c], a, 0, 0, 0);
                a = __builtin_amdgcn_mfma_f32_16x16x32_bf16(Ah[rt], Bl[kt][c], a, 0, 0, 0);
                a = __builtin_amdgcn_mfma_f32_16x16x32_bf16(Al[rt], Bh[kt][c], a, 0, 0, 0);
                acc[rt][c] = a;
            }
    }

    // ---- epilogue: D layout col=lane&15, row=(lane>>4)*4+reg (verified map)
    const int c0    = w * 32 + (lane & 15);
    float* db       = (w < 2) ? out : pb;
    const int cbase = (w < 2) ? c0 : c0 - OC;
    const int r0    = (lane >> 4) * 4;
#pragma unroll
    for (int rt = 0; rt < 4; ++rt)
#pragma unroll
        for (int c = 0; c < 2; ++c)
#pragma unroll
            for (int reg = 0; reg < 4; ++reg) {
                const int node = n0 + rt * 16 + r0 + reg;
                if (node < N_NODES)
                    db[(long)node * OC + cbase + c * 16] = acc[rt][c][reg];
            }
}

// ---------------------------------------------------------------------------
// Histogram + rank capture: rank[e] = arrival index of edge e within src[e].
__global__ void k_hist(const int* __restrict__ src, int* __restrict__ cnt,
                       int* __restrict__ rank) {
    const int e = blockIdx.x * blockDim.x + threadIdx.x;
    if (e < N_EDGES) rank[e] = atomicAdd(&cnt[src[e]], 1);
}

__global__ __launch_bounds__(256) void k_scan_blk(
    const int* __restrict__ cnt, int* __restrict__ row, int* __restrict__ bsum)
{
    __shared__ int sh[256];
    const int t = threadIdx.x;
    const int base = blockIdx.x * SCAN_CHUNK + t * 4;
    int c0 = 0, c1 = 0, c2 = 0, c3 = 0;
    if (base + 3 < N_NODES) {
        const int4 c = *(const int4*)(cnt + base);
        c0 = c.x; c1 = c.y; c2 = c.z; c3 = c.w;
    } else {
        if (base + 0 < N_NODES) c0 = cnt[base + 0];
        if (base + 1 < N_NODES) c1 = cnt[base + 1];
        if (base + 2 < N_NODES) c2 = cnt[base + 2];
    }
    const int s = c0 + c1 + c2 + c3;
    sh[t] = s;
    __syncthreads();
    for (int off = 1; off < 256; off <<= 1) {
        int v = sh[t];
        int a = (t >= off) ? sh[t - off] : 0;
        __syncthreads();
        sh[t] = v + a;
        __syncthreads();
    }
    const int excl = sh[t] - s;
    if (t == 255) bsum[blockIdx.x] = sh[255];
    if (base + 3 < N_NODES) {
        int4 r;
        r.x = excl; r.y = excl + c0; r.z = excl + c0 + c1; r.w = excl + c0 + c1 + c2;
        *(int4*)(row + base) = r;
    } else {
        int e = excl;
        if (base + 0 < N_NODES) { row[base + 0] = e; e += c0; }
        if (base + 1 < N_NODES) { row[base + 1] = e; e += c1; }
        if (base + 2 < N_NODES) { row[base + 2] = e; }
    }
}

__global__ void k_scan_top(int* __restrict__ bsum, int* __restrict__ row) {
    __shared__ int sh[128];
    const int t = threadIdx.x;
    const int v = (t < SCAN_BLOCKS) ? bsum[t] : 0;
    sh[t] = v;
    __syncthreads();
    for (int off = 1; off < 128; off <<= 1) {
        int x = sh[t];
        int a = (t >= off) ? sh[t - off] : 0;
        __syncthreads();
        sh[t] = x + a;
        __syncthreads();
    }
    if (t < SCAN_BLOCKS) bsum[t] = sh[t] - v;
    if (t == 127) row[N_NODES] = sh[127];
}

__global__ __launch_bounds__(256) void k_scan_add(
    int* __restrict__ row, const int* __restrict__ bsum)
{
    const int off = bsum[blockIdx.x];
    const int base = blockIdx.x * SCAN_CHUNK + threadIdx.x * 4;
    if (base + 3 < N_NODES) {
        int4 r = *(const int4*)(row + base);
        r.x += off; r.y += off; r.z += off; r.w += off;
        *(int4*)(row + base) = r;
    } else {
#pragma unroll
        for (int k = 0; k < 4; ++k)
            if (base + k < N_NODES)
                row[base + k] += off;
    }
}

// ---------------------------------------------------------------------------
// Permutation scatter (4B/edge, the ONLY scattered write in the pipeline):
// perm[row[src[e]] + rank[e]] = e.
__global__ void k_perm(const int* __restrict__ src, const int* __restrict__ rank,
                       const int* __restrict__ row, int* __restrict__ perm) {
    const int e = blockIdx.x * blockDim.x + threadIdx.x;
    if (e < N_EDGES) perm[row[src[e]] + rank[e]] = e;
}

// ---------------------------------------------------------------------------
// Edge record build in EDGE order (fully coalesced 8B stores, NO scatter):
// rec8[e] = {inv_bits, dst}.
__global__ void k_prep8(const int* __restrict__ src, const int* __restrict__ dst,
                        const float4* __restrict__ xyz, uint2* __restrict__ rec8)
{
    const int e = blockIdx.x * blockDim.x + threadIdx.x;
    if (e >= N_EDGES) return;
    const int s = src[e];
    const int d = dst[e];
    const float4 a = xyz[s], b = xyz[d];          // L2-resident gathers
    const float dx = a.x - b.x, dy = a.y - b.y, dz = a.z - b.z;
    const float d2 = dx * dx + dy * dy + dz * dz;
    const float inv = (d2 > 0.f) ? __builtin_amdgcn_rcpf(d2) : 1.0e4f;
    rec8[e] = make_uint2(__float_as_uint(inv), (unsigned)d);
}

// ---------------------------------------------------------------------------
// Per-node bond segment-sum (f32 accumulate, bf16-pair packed output).
// Wave per node; lanes 0..10 each own a bond channel pair; edges via perm
// (one ~88B line per edge, cache-served, 4-edge unroll).
__global__ __launch_bounds__(256) void k_bsum(
    const int* __restrict__ row, const int* __restrict__ perm,
    const float* __restrict__ bond, unsigned* __restrict__ bs)
{
    const int lane = threadIdx.x & 63;
    const int wid  = (int)((blockIdx.x * blockDim.x + threadIdx.x) >> 6);
    if (wid >= N_NODES) return;
    const int n = __builtin_amdgcn_readfirstlane(wid);
    const int rs = row[n], re = row[n + 1];

    float sx = 0.f, sy = 0.f;
    int i = rs;
    for (; i + 4 <= re; i += 4) {
        int pe[4];
#pragma unroll
        for (int u = 0; u < 4; ++u)
            pe[u] = __builtin_amdgcn_readfirstlane(clampe(perm[i + u]));
        if (lane < 11) {
            float2 v[4];
#pragma unroll
            for (int u = 0; u < 4; ++u)
                v[u] = *(const float2*)(bond + (size_t)pe[u] * NB + 2 * lane);
#pragma unroll
            for (int u = 0; u < 4; ++u) { sx += v[u].x; sy += v[u].y; }
        }
    }
    for (; i < re; ++i) {
        const int pe = __builtin_amdgcn_readfirstlane(clampe(perm[i]));
        if (lane < 11) {
            const float2 v = *(const float2*)(bond + (size_t)pe * NB + 2 * lane);
            sx += v.x; sy += v.y;
        }
    }
    if (lane < 11)
        bs[n * 12 + lane] = pk_bf16(sx, sy);
}

// ---------------------------------------------------------------------------
// Gather, slim: per edge just inv*pb[dst] (+scalar inv_sum); bond contribution
// applied once per node from the precomputed segment-sum bs[n].
// Edge records accessed via perm indirection (R6-proven pattern).
__global__ __launch_bounds__(256) void k_gather(
    const int* __restrict__ row, const int* __restrict__ perm,
    const uint2* __restrict__ rec8, const unsigned* __restrict__ bs,
    const float* __restrict__ w_n, const float* __restrict__ pb,
    const float4* __restrict__ xyz, float* __restrict__ out)
{
    const int lane = threadIdx.x & 63;
    const int wid  = (int)((blockIdx.x * blockDim.x + threadIdx.x) >> 6);
    if (wid >= N_NODES) return;
    const int n = __builtin_amdgcn_readfirstlane(wid);

    // per-lane w_n bond columns, packed bf16 pairs (matches bs packing)
    unsigned wp[11];
#pragma unroll
    for (int j = 0; j < 11; ++j)
        wp[j] = pk_bf16(w_n[(NF + 2 * j) * OC + lane],
                        w_n[(NF + 2 * j + 1) * OC + lane]);
    const float w0 = w_n[0 * OC + lane];
    const float w1 = w_n[1 * OC + lane];
    const float w2 = w_n[2 * OC + lane];

    const int rs = row[n], re = row[n + 1];
    const float4 xs = xyz[n];
    const float pa = pb[(long)n * OC + lane]
                   - (xs.x * w0 + xs.y * w1 + xs.z * w2);

    float acc = 0.f;
    float inv_sum = 0.f;
    int i = rs;

    // ---- main loop: 8 edges in flight
    for (; i + 8 <= re; i += 8) {
        int pe[8];
#pragma unroll
        for (int u = 0; u < 8; ++u)
            pe[u] = __builtin_amdgcn_readfirstlane(clampe(perm[i + u]));
        uint2 r[8];
#pragma unroll
        for (int u = 0; u < 8; ++u) r[u] = rec8[pe[u]];
        float pbt[8];
#pragma unroll
        for (int u = 0; u < 8; ++u)
            pbt[u] = pb[(long)(int)r[u].y * OC + lane];
#pragma unroll
        for (int u = 0; u < 8; ++u) {
            const float inv = __uint_as_float(r[u].x);
            acc += inv * pbt[u];
            inv_sum += inv;
        }
    }
    // ---- tail
    for (; i < re; ++i) {
        const int pe = __builtin_amdgcn_readfirstlane(clampe(perm[i]));
        const uint2 r = rec8[pe];
        const float inv = __uint_as_float(r.x);
        acc += inv * pb[(long)(int)r.y * OC + lane];
        inv_sum += inv;
    }
    acc += pa * inv_sum;

    // ---- per-node bond epilogue: 11 dot2 with packed segment sums
    const unsigned* bsn = bs + n * 12;
    float bc = 0.f;
#pragma unroll
    for (int j = 0; j < 11; ++j)
        bc = dot2b(bsn[j], wp[j], bc);

    out[(long)n * OC + lane] += acc + bc;
}

// ---------------------------------------------------------------------------
extern "C" void kernel_launch(void* const* d_in, const int* in_sizes, int n_in,
                              void* d_out, int out_size, void* d_ws, size_t ws_size,
                              hipStream_t stream) {
    const float* feat = (const float*)d_in[0];
    const float* bond = (const float*)d_in[1];
    const float* w_s  = (const float*)d_in[2];
    const float* w_n  = (const float*)d_in[3];
    const int*   src  = (const int*)d_in[4];
    const int*   dstv = (const int*)d_in[5];
    float* out = (float*)d_out;

    // workspace layout (16B-aligned), ~45.7 MB total. NO aliasing anywhere.
    char* base = (char*)d_ws;
    float*    pb     = (float*)   (base);                 // 25,600,000
    float4*   xyz    = (float4*)  (base + 25600000);      //  1,600,000
    int*      row    = (int*)     (base + 27200000);      //    400,016
    int*      cnt    = (int*)     (base + 27600016);      //    400,000
    int*      rank   = (int*)     (base + 28000016);      //  3,200,000
    int*      bsc    = (int*)     (base + 31200016);      //        560 (pad)
    short*    btw    = (short*)   (base + 31200640);      //     49,152 (dedicated B^T)
    uint2*    rec8   = (uint2*)   (base + 31249792);      //  6,400,000 (8B/edge)
    int*      perm   = (int*)     (base + 37649792);      //  3,200,000
    unsigned* bsv    = (unsigned*)(base + 40849792);      //  4,800,000 (12 u32/node)

    hipMemsetAsync(cnt, 0, N_NODES * sizeof(int), stream);

    k_wprep   <<<48, 256, 0, stream>>>(w_s, w_n, btw);
    k_node_mfma<<<(N_NODES + 63) / 64, 256, 0, stream>>>(feat, btw, out, pb, xyz);
    k_hist    <<<(N_EDGES + 255) / 256, 256, 0, stream>>>(src, cnt, rank);
    k_scan_blk<<<SCAN_BLOCKS, 256, 0, stream>>>(cnt, row, bsc);
    k_scan_top<<<1, 128, 0, stream>>>(bsc, row);
    k_scan_add<<<SCAN_BLOCKS, 256, 0, stream>>>(row, bsc);
    k_perm    <<<(N_EDGES + 255) / 256, 256, 0, stream>>>(src, rank, row, perm);
    k_prep8   <<<(N_EDGES + 255) / 256, 256, 0, stream>>>(src, dstv, xyz, rec8);
    k_bsum    <<<(N_NODES * 64 + 255) / 256, 256, 0, stream>>>(row, perm, bond, bsv);
    k_gather  <<<(N_NODES * 64 + 255) / 256, 256, 0, stream>>>(row, perm, rec8,
                                                               bsv, w_n, pb,
                                                               xyz, out);
}

// Round 10
// 313.758 us; speedup vs baseline: 1.0649x; 1.0649x over previous
//
#include <hip/hip_runtime.h>

#define N_NODES 100000
#define N_EDGES 800000
#define NF 81
#define NB 22
#define OC 64
#define SCAN_CHUNK 1024
#define SCAN_BLOCKS ((N_NODES + SCAN_CHUNK - 1) / SCAN_CHUNK)   // 98

typedef __attribute__((ext_vector_type(8))) short bf16x8;
typedef __attribute__((ext_vector_type(4))) float f32x4;

#if defined(__has_builtin)
#if __has_builtin(__builtin_amdgcn_fdot2_f32_bf16)
#define HAVE_FDOT2 1
#endif
#endif

#ifdef HAVE_FDOT2
typedef __attribute__((ext_vector_type(2))) __bf16 bfv2;
#endif

// dot2: c += lo(a)*lo(b) + hi(a)*hi(b), operands are packed bf16 pairs
__device__ inline float dot2b(unsigned a, unsigned b, float c) {
#ifdef HAVE_FDOT2
    return __builtin_amdgcn_fdot2_f32_bf16(__builtin_bit_cast(bfv2, a),
                                           __builtin_bit_cast(bfv2, b), c, false);
#else
    return c + __uint_as_float(a << 16)         * __uint_as_float(b << 16)
             + __uint_as_float(a & 0xffff0000u) * __uint_as_float(b & 0xffff0000u);
#endif
}

// round-to-nearest-even fp32 -> bf16 (high part), returns residual in rest
__device__ inline unsigned short bfsplit(float v, float& rest) {
    const unsigned b = __float_as_uint(v);
    const unsigned short h = (unsigned short)((b + 0x7fffu + ((b >> 16) & 1u)) >> 16);
    rest = v - __uint_as_float(((unsigned)h) << 16);
    return h;
}

__device__ inline unsigned pk_bf16(float a, float b) {
    const unsigned ua = (__float_as_uint(a) + 0x8000u) >> 16;
    const unsigned ub = (__float_as_uint(b) + 0x8000u) & 0xffff0000u;
    return ua | ub;
}

// defensive index clamp (keeps any corrupt perm value in-bounds)
__device__ inline int clampe(int p) {
    return ((unsigned)p < (unsigned)N_EDGES) ? p : 0;
}

// ---------------------------------------------------------------------------
// Build B^T in bf16 hi/lo: BT[c][k], c in [0,128), k in [0,96).
// DEDICATED workspace region (no aliasing with edge records).
__global__ void k_wprep(const float* __restrict__ w_s, const float* __restrict__ w_n,
                        short* __restrict__ bt)
{
    const int tid = blockIdx.x * blockDim.x + threadIdx.x;
    if (tid >= 128 * 96) return;
    const int c = tid / 96;
    const int k = tid - c * 96;
    float v = 0.f;
    if (k < NF) v = (c < OC) ? w_s[k * OC + c] : w_n[k * OC + (c - OC)];
    float rest, dummy;
    const unsigned short h = bfsplit(v, rest);
    const unsigned short l = bfsplit(rest, dummy);
    bt[c * 96 + k]               = (short)h;          // BT_hi
    bt[128 * 96 + c * 96 + k]    = (short)l;          // BT_lo
}

// ---------------------------------------------------------------------------
// Node GEMM on matrix cores: [out | pb] = feat @ [w_s | w_n[:81]]
// Split-bf16 3-pass MFMA (Ah*Bh + Ah*Bl + Al*Bh) -> ~2^-17 relative error.
__global__ __launch_bounds__(256) void k_node_mfma(
    const float* __restrict__ feat, const short* __restrict__ bt,
    float* __restrict__ out, float* __restrict__ pb, float4* __restrict__ xyz)
{
    __shared__ short shA[2 * 64 * 104];               // hi at 0, lo at 6656 (26.6 KB)
    const int t    = threadIdx.x;
    const int lane = t & 63;
    const int w    = t >> 6;
    const int n0   = blockIdx.x * 64;

    // ---- B fragments from global B^T (L2-resident, 16B-aligned b128 loads)
    const int krow = (lane >> 4) * 8;                 // k offset within 32-k tile
    bf16x8 Bh[3][2], Bl[3][2];
#pragma unroll
    for (int kt = 0; kt < 3; ++kt)
#pragma unroll
        for (int c = 0; c < 2; ++c) {
            const int col = w * 32 + c * 16 + (lane & 15);
            const int off = col * 96 + kt * 32 + krow;
            Bh[kt][c] = *(const bf16x8*)(bt + off);
            Bl[kt][c] = *(const bf16x8*)(bt + 128 * 96 + off);
        }

    // ---- stage A (64 rows x 81 k) as bf16 hi/lo into LDS
    const long gbase = (long)n0 * NF;
    const long gmax  = (long)N_NODES * NF;
    for (int j = t; j < (64 * NF) / 4; j += 256) {    // 1296 float4s
        const int flat = j * 4;
        float v[4];
        if (gbase + flat + 3 < gmax) {
            const float4 q = *(const float4*)(feat + gbase + flat);
            v[0] = q.x; v[1] = q.y; v[2] = q.z; v[3] = q.w;
        } else {
#pragma unroll
            for (int i = 0; i < 4; ++i)
                v[i] = (gbase + flat + i < gmax) ? feat[gbase + flat + i] : 0.f;
        }
#pragma unroll
        for (int i = 0; i < 4; ++i) {
            const int fi  = flat + i;
            const int row = (int)((unsigned)fi / 81u);
            const int k   = fi - row * 81;
            float rest, dummy;
            const unsigned short h = bfsplit(v[i], rest);
            const unsigned short l = bfsplit(rest, dummy);
            shA[row * 104 + k]        = (short)h;
            shA[6656 + row * 104 + k] = (short)l;
        }
    }
    // zero K padding 81..96 (frags read up to k=95)
    for (int j = t; j < 64 * 16; j += 256) {
        const int row = j >> 4, k = NF + (j & 15);
        shA[row * 104 + k] = 0;
        shA[6656 + row * 104 + k] = 0;
    }

    // xyz in exact fp32 (distance path must stay fp32-accurate)
    if (t < 64 && n0 + t < N_NODES) {
        const float* fp = feat + (long)(n0 + t) * NF;
        xyz[n0 + t] = make_float4(fp[0], fp[1], fp[2], 0.f);
    }
    __syncthreads();

    // ---- MFMA: 4 row-tiles x 2 col-tiles x 3 k-tiles x 3 passes
    f32x4 acc[4][2];
#pragma unroll
    for (int rt = 0; rt < 4; ++rt)
#pragma unroll
        for (int c = 0; c < 2; ++c)
            acc[rt][c] = (f32x4){0.f, 0.f, 0.f, 0.f};

#pragma unroll
    for (int kt = 0; kt < 3; ++kt) {
        bf16x8 Ah[4], Al[4];
#pragma unroll
        for (int rt = 0; rt < 4; ++rt) {
            const int o = (rt * 16 + (lane & 15)) * 104 + kt * 32 + krow;
            Ah[rt] = *(const bf16x8*)(shA + o);
            Al[rt] = *(const bf16x8*)(shA + 6656 + o);
        }
#pragma unroll
        for (int rt = 0; rt < 4; ++rt)
#pragma unroll
            for (int c = 0; c < 2; ++c) {
                f32x4 a = acc[rt][c];
                a = __builtin_amdgcn_mfma_f32_16x16x32_bf16(Ah[rt], Bh[kt][c], a, 0, 0, 0);
                a = __builtin_amdgcn_mfma_f32_16x16x32_bf16(Ah[rt], Bl[kt][c], a, 0, 0, 0);
                a = __builtin_amdgcn_mfma_f32_16x16x32_bf16(Al[rt], Bh[kt][c], a, 0, 0, 0);
                acc[rt][c] = a;
            }
    }

    // ---- epilogue: D layout col=lane&15, row=(lane>>4)*4+reg (verified map)
    const int c0    = w * 32 + (lane & 15);
    float* db       = (w < 2) ? out : pb;
    const int cbase = (w < 2) ? c0 : c0 - OC;
    const int r0    = (lane >> 4) * 4;
#pragma unroll
    for (int rt = 0; rt < 4; ++rt)
#pragma unroll
        for (int c = 0; c < 2; ++c)
#pragma unroll
            for (int reg = 0; reg < 4; ++reg) {
                const int node = n0 + rt * 16 + r0 + reg;
                if (node < N_NODES)
                    db[(long)node * OC + cbase + c * 16] = acc[rt][c][reg];
            }
}

// ---------------------------------------------------------------------------
// Histogram + rank capture: rank[e] = arrival index of edge e within src[e].
__global__ void k_hist(const int* __restrict__ src, int* __restrict__ cnt,
                       int* __restrict__ rank) {
    const int e = blockIdx.x * blockDim.x + threadIdx.x;
    if (e < N_EDGES) rank[e] = atomicAdd(&cnt[src[e]], 1);
}

__global__ __launch_bounds__(256) void k_scan_blk(
    const int* __restrict__ cnt, int* __restrict__ row, int* __restrict__ bsum)
{
    __shared__ int sh[256];
    const int t = threadIdx.x;
    const int base = blockIdx.x * SCAN_CHUNK + t * 4;
    int c0 = 0, c1 = 0, c2 = 0, c3 = 0;
    if (base + 3 < N_NODES) {
        const int4 c = *(const int4*)(cnt + base);
        c0 = c.x; c1 = c.y; c2 = c.z; c3 = c.w;
    } else {
        if (base + 0 < N_NODES) c0 = cnt[base + 0];
        if (base + 1 < N_NODES) c1 = cnt[base + 1];
        if (base + 2 < N_NODES) c2 = cnt[base + 2];
    }
    const int s = c0 + c1 + c2 + c3;
    sh[t] = s;
    __syncthreads();
    for (int off = 1; off < 256; off <<= 1) {
        int v = sh[t];
        int a = (t >= off) ? sh[t - off] : 0;
        __syncthreads();
        sh[t] = v + a;
        __syncthreads();
    }
    const int excl = sh[t] - s;
    if (t == 255) bsum[blockIdx.x] = sh[255];
    if (base + 3 < N_NODES) {
        int4 r;
        r.x = excl; r.y = excl + c0; r.z = excl + c0 + c1; r.w = excl + c0 + c1 + c2;
        *(int4*)(row + base) = r;
    } else {
        int e = excl;
        if (base + 0 < N_NODES) { row[base + 0] = e; e += c0; }
        if (base + 1 < N_NODES) { row[base + 1] = e; e += c1; }
        if (base + 2 < N_NODES) { row[base + 2] = e; }
    }
}

__global__ void k_scan_top(int* __restrict__ bsum, int* __restrict__ row) {
    __shared__ int sh[128];
    const int t = threadIdx.x;
    const int v = (t < SCAN_BLOCKS) ? bsum[t] : 0;
    sh[t] = v;
    __syncthreads();
    for (int off = 1; off < 128; off <<= 1) {
        int x = sh[t];
        int a = (t >= off) ? sh[t - off] : 0;
        __syncthreads();
        sh[t] = x + a;
        __syncthreads();
    }
    if (t < SCAN_BLOCKS) bsum[t] = sh[t] - v;
    if (t == 127) row[N_NODES] = sh[127];
}

__global__ __launch_bounds__(256) void k_scan_add(
    int* __restrict__ row, const int* __restrict__ bsum)
{
    const int off = bsum[blockIdx.x];
    const int base = blockIdx.x * SCAN_CHUNK + threadIdx.x * 4;
    if (base + 3 < N_NODES) {
        int4 r = *(const int4*)(row + base);
        r.x += off; r.y += off; r.z += off; r.w += off;
        *(int4*)(row + base) = r;
    } else {
#pragma unroll
        for (int k = 0; k < 4; ++k)
            if (base + k < N_NODES)
                row[base + k] += off;
    }
}

// ---------------------------------------------------------------------------
// Permutation scatter (4B/edge, the ONLY scattered write in the pipeline):
// perm[row[src[e]] + rank[e]] = e.
__global__ void k_perm(const int* __restrict__ src, const int* __restrict__ rank,
                       const int* __restrict__ row, int* __restrict__ perm) {
    const int e = blockIdx.x * blockDim.x + threadIdx.x;
    if (e < N_EDGES) perm[row[src[e]] + rank[e]] = e;
}

// ---------------------------------------------------------------------------
// Sorted record build: rec8s[i] = {inv, dst} for edge perm[i].
// Reads perm coalesced; src/dst/xyz random but L2-resident (<=3.2 MB each);
// write fully sequential. Replaces the old k_prep8 + gather-side indirection.
__global__ void k_sortrec(const int* __restrict__ perm, const int* __restrict__ src,
                          const int* __restrict__ dst, const float4* __restrict__ xyz,
                          uint2* __restrict__ rec8s)
{
    const int i = blockIdx.x * blockDim.x + threadIdx.x;
    if (i >= N_EDGES) return;
    const int e = clampe(perm[i]);
    const int s = src[e];
    const int d = dst[e];
    const float4 a = xyz[s], b = xyz[d];
    const float dx = a.x - b.x, dy = a.y - b.y, dz = a.z - b.z;
    const float d2 = dx * dx + dy * dy + dz * dz;
    const float inv = (d2 > 0.f) ? __builtin_amdgcn_rcpf(d2) : 1.0e4f;
    rec8s[i] = make_uint2(__float_as_uint(inv), (unsigned)d);
}

// ---------------------------------------------------------------------------
// Per-node bond segment-sum, 2 edges per pass (lanes 0..21 edge A, 32..53
// edge B -> 44/64 lanes), 8 edges in flight, __shfl_xor(32) half-combine.
__global__ __launch_bounds__(256) void k_bsum(
    const int* __restrict__ row, const int* __restrict__ perm,
    const float* __restrict__ bond, unsigned* __restrict__ bs)
{
    const int lane = threadIdx.x & 63;
    const int wid  = (int)((blockIdx.x * blockDim.x + threadIdx.x) >> 6);
    if (wid >= N_NODES) return;
    const int n = __builtin_amdgcn_readfirstlane(wid);
    const int rs = row[n], re = row[n + 1];

    const int h = lane >> 5;          // 0: edge A slot, 1: edge B slot
    const int c = lane & 31;          // bond channel (active if c < 22)

    float s = 0.f;
    int i = rs;
    // ---- 8 edges per pass (4 A/B pairs in flight)
    for (; i + 8 <= re; i += 8) {
        int pes[8];
#pragma unroll
        for (int u = 0; u < 8; ++u)
            pes[u] = __builtin_amdgcn_readfirstlane(clampe(perm[i + u]));
        if (c < 22) {
            float v[4];
#pragma unroll
            for (int u = 0; u < 4; ++u)
                v[u] = bond[(size_t)pes[2 * u + h] * NB + c];
#pragma unroll
            for (int u = 0; u < 4; ++u) s += v[u];
        }
    }
    // ---- 2 edges per pass
    for (; i + 2 <= re; i += 2) {
        const int peA = __builtin_amdgcn_readfirstlane(clampe(perm[i]));
        const int peB = __builtin_amdgcn_readfirstlane(clampe(perm[i + 1]));
        if (c < 22)
            s += bond[(size_t)(h ? peB : peA) * NB + c];
    }
    // ---- single tail
    if (i < re) {
        const int pe = __builtin_amdgcn_readfirstlane(clampe(perm[i]));
        if (h == 0 && c < 22)
            s += bond[(size_t)pe * NB + c];
    }

    // combine halves: lane L gets s(L) + s(L^32) -> full channel sums on 0..21
    const float st = s + __shfl_xor(s, 32);
    // pack channel pairs (2j, 2j+1) on lanes 0..10
    const float a = __shfl(st, 2 * lane);
    const float b = __shfl(st, 2 * lane + 1);
    if (lane < 11)
        bs[n * 12 + lane] = pk_bf16(a, b);
}

// ---------------------------------------------------------------------------
// Gather, slim: sequential rec8s reads (no indirection), 8/4/1 loop tiering.
// Per edge: inv*pb[dst] (+scalar inv_sum); bond applied once per node.
__global__ __launch_bounds__(256) void k_gather(
    const int* __restrict__ row, const uint2* __restrict__ rec8s,
    const unsigned* __restrict__ bs, const float* __restrict__ w_n,
    const float* __restrict__ pb, const float4* __restrict__ xyz,
    float* __restrict__ out)
{
    const int lane = threadIdx.x & 63;
    const int wid  = (int)((blockIdx.x * blockDim.x + threadIdx.x) >> 6);
    if (wid >= N_NODES) return;
    const int n = __builtin_amdgcn_readfirstlane(wid);

    // per-lane w_n bond columns, packed bf16 pairs (matches bs packing)
    unsigned wp[11];
#pragma unroll
    for (int j = 0; j < 11; ++j)
        wp[j] = pk_bf16(w_n[(NF + 2 * j) * OC + lane],
                        w_n[(NF + 2 * j + 1) * OC + lane]);
    const float w0 = w_n[0 * OC + lane];
    const float w1 = w_n[1 * OC + lane];
    const float w2 = w_n[2 * OC + lane];

    const int rs = row[n], re = row[n + 1];
    const float4 xs = xyz[n];
    const float pa = pb[(long)n * OC + lane]
                   - (xs.x * w0 + xs.y * w1 + xs.z * w2);

    float acc = 0.f;
    float inv_sum = 0.f;
    const uint2* rp = rec8s + rs;
    const int m = re - rs;
    int i = 0;

    // ---- 8 edges in flight
    for (; i + 8 <= m; i += 8) {
        uint2 r[8];
#pragma unroll
        for (int u = 0; u < 8; ++u) r[u] = rp[i + u];
        float pbt[8];
#pragma unroll
        for (int u = 0; u < 8; ++u)
            pbt[u] = pb[(long)(int)r[u].y * OC + lane];
#pragma unroll
        for (int u = 0; u < 8; ++u) {
            const float inv = __uint_as_float(r[u].x);
            acc += inv * pbt[u];
            inv_sum += inv;
        }
    }
    // ---- 4 edges in flight
    for (; i + 4 <= m; i += 4) {
        uint2 r[4];
#pragma unroll
        for (int u = 0; u < 4; ++u) r[u] = rp[i + u];
        float pbt[4];
#pragma unroll
        for (int u = 0; u < 4; ++u)
            pbt[u] = pb[(long)(int)r[u].y * OC + lane];
#pragma unroll
        for (int u = 0; u < 4; ++u) {
            const float inv = __uint_as_float(r[u].x);
            acc += inv * pbt[u];
            inv_sum += inv;
        }
    }
    // ---- singles
    for (; i < m; ++i) {
        const uint2 r = rp[i];
        const float inv = __uint_as_float(r.x);
        acc += inv * pb[(long)(int)r.y * OC + lane];
        inv_sum += inv;
    }
    acc += pa * inv_sum;

    // ---- per-node bond epilogue: 11 dot2 with packed segment sums
    const unsigned* bsn = bs + n * 12;
    float bc = 0.f;
#pragma unroll
    for (int j = 0; j < 11; ++j)
        bc = dot2b(bsn[j], wp[j], bc);

    out[(long)n * OC + lane] += acc + bc;
}

// ---------------------------------------------------------------------------
extern "C" void kernel_launch(void* const* d_in, const int* in_sizes, int n_in,
                              void* d_out, int out_size, void* d_ws, size_t ws_size,
                              hipStream_t stream) {
    const float* feat = (const float*)d_in[0];
    const float* bond = (const float*)d_in[1];
    const float* w_s  = (const float*)d_in[2];
    const float* w_n  = (const float*)d_in[3];
    const int*   src  = (const int*)d_in[4];
    const int*   dstv = (const int*)d_in[5];
    float* out = (float*)d_out;

    // workspace layout (16B-aligned), ~45.7 MB total. NO aliasing anywhere.
    char* base = (char*)d_ws;
    float*    pb     = (float*)   (base);                 // 25,600,000
    float4*   xyz    = (float4*)  (base + 25600000);      //  1,600,000
    int*      row    = (int*)     (base + 27200000);      //    400,016
    int*      cnt    = (int*)     (base + 27600016);      //    400,000
    int*      rank   = (int*)     (base + 28000016);      //  3,200,000
    int*      bsc    = (int*)     (base + 31200016);      //        560 (pad)
    short*    btw    = (short*)   (base + 31200640);      //     49,152 (dedicated B^T)
    uint2*    rec8s  = (uint2*)   (base + 31249792);      //  6,400,000 (8B/edge, sorted)
    int*      perm   = (int*)     (base + 37649792);      //  3,200,000
    unsigned* bsv    = (unsigned*)(base + 40849792);      //  4,800,000 (12 u32/node)

    hipMemsetAsync(cnt, 0, N_NODES * sizeof(int), stream);

    k_wprep   <<<48, 256, 0, stream>>>(w_s, w_n, btw);
    k_node_mfma<<<(N_NODES + 63) / 64, 256, 0, stream>>>(feat, btw, out, pb, xyz);
    k_hist    <<<(N_EDGES + 255) / 256, 256, 0, stream>>>(src, cnt, rank);
    k_scan_blk<<<SCAN_BLOCKS, 256, 0, stream>>>(cnt, row, bsc);
    k_scan_top<<<1, 128, 0, stream>>>(bsc, row);
    k_scan_add<<<SCAN_BLOCKS, 256, 0, stream>>>(row, bsc);
    k_perm    <<<(N_EDGES + 255) / 256, 256, 0, stream>>>(src, rank, row, perm);
    k_sortrec <<<(N_EDGES + 255) / 256, 256, 0, stream>>>(perm, src, dstv, xyz,
                                                          rec8s);
    k_bsum    <<<(N_NODES * 64 + 255) / 256, 256, 0, stream>>>(row, perm, bond, bsv);
    k_gather  <<<(N_NODES * 64 + 255) / 256, 256, 0, stream>>>(row, rec8s, bsv,
                                                               w_n, pb, xyz, out);
}

// Round 11
// 302.616 us; speedup vs baseline: 1.1041x; 1.0368x over previous
//
#include <hip/hip_runtime.h>

#define N_NODES 100000
#define N_EDGES 800000
#define NF 81
#define NB 22
#define OC 64
#define SCAN_CHUNK 1024
#define SCAN_BLOCKS ((N_NODES + SCAN_CHUNK - 1) / SCAN_CHUNK)   // 98

typedef __attribute__((ext_vector_type(8))) short bf16x8;
typedef __attribute__((ext_vector_type(4))) float f32x4;

// round-to-nearest-even fp32 -> bf16 (high part), returns residual in rest
__device__ inline unsigned short bfsplit(float v, float& rest) {
    const unsigned b = __float_as_uint(v);
    const unsigned short h = (unsigned short)((b + 0x7fffu + ((b >> 16) & 1u)) >> 16);
    rest = v - __uint_as_float(((unsigned)h) << 16);
    return h;
}

// defensive index clamp (keeps any corrupt perm value in-bounds)
__device__ inline int clampe(int p) {
    return ((unsigned)p < (unsigned)N_EDGES) ? p : 0;
}

// ---------------------------------------------------------------------------
// Build B^T in bf16 hi/lo: BT[c][k], c in [0,128), k in [0,96).
// DEDICATED workspace region (no aliasing with edge records).
__global__ void k_wprep(const float* __restrict__ w_s, const float* __restrict__ w_n,
                        short* __restrict__ bt)
{
    const int tid = blockIdx.x * blockDim.x + threadIdx.x;
    if (tid >= 128 * 96) return;
    const int c = tid / 96;
    const int k = tid - c * 96;
    float v = 0.f;
    if (k < NF) v = (c < OC) ? w_s[k * OC + c] : w_n[k * OC + (c - OC)];
    float rest, dummy;
    const unsigned short h = bfsplit(v, rest);
    const unsigned short l = bfsplit(rest, dummy);
    bt[c * 96 + k]               = (short)h;          // BT_hi
    bt[128 * 96 + c * 96 + k]    = (short)l;          // BT_lo
}

// ---------------------------------------------------------------------------
// Node GEMM on matrix cores: [out | pb] = feat @ [w_s | w_n[:81]]
// Split-bf16 3-pass MFMA (Ah*Bh + Ah*Bl + Al*Bh) -> ~2^-17 relative error.
__global__ __launch_bounds__(256) void k_node_mfma(
    const float* __restrict__ feat, const short* __restrict__ bt,
    float* __restrict__ out, float* __restrict__ pb, float4* __restrict__ xyz)
{
    __shared__ short shA[2 * 64 * 104];               // hi at 0, lo at 6656 (26.6 KB)
    const int t    = threadIdx.x;
    const int lane = t & 63;
    const int w    = t >> 6;
    const int n0   = blockIdx.x * 64;

    // ---- B fragments from global B^T (L2-resident, 16B-aligned b128 loads)
    const int krow = (lane >> 4) * 8;                 // k offset within 32-k tile
    bf16x8 Bh[3][2], Bl[3][2];
#pragma unroll
    for (int kt = 0; kt < 3; ++kt)
#pragma unroll
        for (int c = 0; c < 2; ++c) {
            const int col = w * 32 + c * 16 + (lane & 15);
            const int off = col * 96 + kt * 32 + krow;
            Bh[kt][c] = *(const bf16x8*)(bt + off);
            Bl[kt][c] = *(const bf16x8*)(bt + 128 * 96 + off);
        }

    // ---- stage A (64 rows x 81 k) as bf16 hi/lo into LDS
    const long gbase = (long)n0 * NF;
    const long gmax  = (long)N_NODES * NF;
    for (int j = t; j < (64 * NF) / 4; j += 256) {    // 1296 float4s
        const int flat = j * 4;
        float v[4];
        if (gbase + flat + 3 < gmax) {
            const float4 q = *(const float4*)(feat + gbase + flat);
            v[0] = q.x; v[1] = q.y; v[2] = q.z; v[3] = q.w;
        } else {
#pragma unroll
            for (int i = 0; i < 4; ++i)
                v[i] = (gbase + flat + i < gmax) ? feat[gbase + flat + i] : 0.f;
        }
#pragma unroll
        for (int i = 0; i < 4; ++i) {
            const int fi  = flat + i;
            const int row = (int)((unsigned)fi / 81u);
            const int k   = fi - row * 81;
            float rest, dummy;
            const unsigned short h = bfsplit(v[i], rest);
            const unsigned short l = bfsplit(rest, dummy);
            shA[row * 104 + k]        = (short)h;
            shA[6656 + row * 104 + k] = (short)l;
        }
    }
    // zero K padding 81..96 (frags read up to k=95)
    for (int j = t; j < 64 * 16; j += 256) {
        const int row = j >> 4, k = NF + (j & 15);
        shA[row * 104 + k] = 0;
        shA[6656 + row * 104 + k] = 0;
    }

    // xyz in exact fp32 (distance path must stay fp32-accurate)
    if (t < 64 && n0 + t < N_NODES) {
        const float* fp = feat + (long)(n0 + t) * NF;
        xyz[n0 + t] = make_float4(fp[0], fp[1], fp[2], 0.f);
    }
    __syncthreads();

    // ---- MFMA: 4 row-tiles x 2 col-tiles x 3 k-tiles x 3 passes
    f32x4 acc[4][2];
#pragma unroll
    for (int rt = 0; rt < 4; ++rt)
#pragma unroll
        for (int c = 0; c < 2; ++c)
            acc[rt][c] = (f32x4){0.f, 0.f, 0.f, 0.f};

#pragma unroll
    for (int kt = 0; kt < 3; ++kt) {
        bf16x8 Ah[4], Al[4];
#pragma unroll
        for (int rt = 0; rt < 4; ++rt) {
            const int o = (rt * 16 + (lane & 15)) * 104 + kt * 32 + krow;
            Ah[rt] = *(const bf16x8*)(shA + o);
            Al[rt] = *(const bf16x8*)(shA + 6656 + o);
        }
#pragma unroll
        for (int rt = 0; rt < 4; ++rt)
#pragma unroll
            for (int c = 0; c < 2; ++c) {
                f32x4 a = acc[rt][c];
                a = __builtin_amdgcn_mfma_f32_16x16x32_bf16(Ah[rt], Bh[kt][c], a, 0, 0, 0);
                a = __builtin_amdgcn_mfma_f32_16x16x32_bf16(Ah[rt], Bl[kt][c], a, 0, 0, 0);
                a = __builtin_amdgcn_mfma_f32_16x16x32_bf16(Al[rt], Bh[kt][c], a, 0, 0, 0);
                acc[rt][c] = a;
            }
    }

    // ---- epilogue: D layout col=lane&15, row=(lane>>4)*4+reg (verified map)
    const int c0    = w * 32 + (lane & 15);
    float* db       = (w < 2) ? out : pb;
    const int cbase = (w < 2) ? c0 : c0 - OC;
    const int r0    = (lane >> 4) * 4;
#pragma unroll
    for (int rt = 0; rt < 4; ++rt)
#pragma unroll
        for (int c = 0; c < 2; ++c)
#pragma unroll
            for (int reg = 0; reg < 4; ++reg) {
                const int node = n0 + rt * 16 + r0 + reg;
                if (node < N_NODES)
                    db[(long)node * OC + cbase + c * 16] = acc[rt][c][reg];
            }
}

// ---------------------------------------------------------------------------
// Histogram + rank capture: rank[e] = arrival index of edge e within src[e].
__global__ void k_hist(const int* __restrict__ src, int* __restrict__ cnt,
                       int* __restrict__ rank) {
    const int e = blockIdx.x * blockDim.x + threadIdx.x;
    if (e < N_EDGES) rank[e] = atomicAdd(&cnt[src[e]], 1);
}

__global__ __launch_bounds__(256) void k_scan_blk(
    const int* __restrict__ cnt, int* __restrict__ row, int* __restrict__ bsum)
{
    __shared__ int sh[256];
    const int t = threadIdx.x;
    const int base = blockIdx.x * SCAN_CHUNK + t * 4;
    int c0 = 0, c1 = 0, c2 = 0, c3 = 0;
    if (base + 3 < N_NODES) {
        const int4 c = *(const int4*)(cnt + base);
        c0 = c.x; c1 = c.y; c2 = c.z; c3 = c.w;
    } else {
        if (base + 0 < N_NODES) c0 = cnt[base + 0];
        if (base + 1 < N_NODES) c1 = cnt[base + 1];
        if (base + 2 < N_NODES) c2 = cnt[base + 2];
    }
    const int s = c0 + c1 + c2 + c3;
    sh[t] = s;
    __syncthreads();
    for (int off = 1; off < 256; off <<= 1) {
        int v = sh[t];
        int a = (t >= off) ? sh[t - off] : 0;
        __syncthreads();
        sh[t] = v + a;
        __syncthreads();
    }
    const int excl = sh[t] - s;
    if (t == 255) bsum[blockIdx.x] = sh[255];
    if (base + 3 < N_NODES) {
        int4 r;
        r.x = excl; r.y = excl + c0; r.z = excl + c0 + c1; r.w = excl + c0 + c1 + c2;
        *(int4*)(row + base) = r;
    } else {
        int e = excl;
        if (base + 0 < N_NODES) { row[base + 0] = e; e += c0; }
        if (base + 1 < N_NODES) { row[base + 1] = e; e += c1; }
        if (base + 2 < N_NODES) { row[base + 2] = e; }
    }
}

__global__ void k_scan_top(int* __restrict__ bsum, int* __restrict__ row) {
    __shared__ int sh[128];
    const int t = threadIdx.x;
    const int v = (t < SCAN_BLOCKS) ? bsum[t] : 0;
    sh[t] = v;
    __syncthreads();
    for (int off = 1; off < 128; off <<= 1) {
        int x = sh[t];
        int a = (t >= off) ? sh[t - off] : 0;
        __syncthreads();
        sh[t] = x + a;
        __syncthreads();
    }
    if (t < SCAN_BLOCKS) bsum[t] = sh[t] - v;
    if (t == 127) row[N_NODES] = sh[127];
}

__global__ __launch_bounds__(256) void k_scan_add(
    int* __restrict__ row, const int* __restrict__ bsum)
{
    const int off = bsum[blockIdx.x];
    const int base = blockIdx.x * SCAN_CHUNK + threadIdx.x * 4;
    if (base + 3 < N_NODES) {
        int4 r = *(const int4*)(row + base);
        r.x += off; r.y += off; r.z += off; r.w += off;
        *(int4*)(row + base) = r;
    } else {
#pragma unroll
        for (int k = 0; k < 4; ++k)
            if (base + k < N_NODES)
                row[base + k] += off;
    }
}

// ---------------------------------------------------------------------------
// Permutation scatter (4B/edge, the ONLY scattered write in the pipeline):
// perm[row[src[e]] + rank[e]] = e.
__global__ void k_perm(const int* __restrict__ src, const int* __restrict__ rank,
                       const int* __restrict__ row, int* __restrict__ perm) {
    const int e = blockIdx.x * blockDim.x + threadIdx.x;
    if (e < N_EDGES) perm[row[src[e]] + rank[e]] = e;
}

// ---------------------------------------------------------------------------
// Sorted record build: rec8s[i] = {inv, dst} for edge perm[i].
// Reads perm coalesced; src/dst/xyz random but L2-resident (<=3.2 MB each);
// write fully sequential.
__global__ void k_sortrec(const int* __restrict__ perm, const int* __restrict__ src,
                          const int* __restrict__ dst, const float4* __restrict__ xyz,
                          uint2* __restrict__ rec8s)
{
    const int i = blockIdx.x * blockDim.x + threadIdx.x;
    if (i >= N_EDGES) return;
    const int e = clampe(perm[i]);
    const int s = src[e];
    const int d = dst[e];
    const float4 a = xyz[s], b = xyz[d];
    const float dx = a.x - b.x, dy = a.y - b.y, dz = a.z - b.z;
    const float d2 = dx * dx + dy * dy + dz * dz;
    const float inv = (d2 > 0.f) ? __builtin_amdgcn_rcpf(d2) : 1.0e4f;
    rec8s[i] = make_uint2(__float_as_uint(inv), (unsigned)d);
}

// ---------------------------------------------------------------------------
// Fused gather: per node, BOTH load streams in one wave:
//   stream 1 (all lanes):   rec8s sequential + pb[dst] random gathers
//   stream 2 (lanes u*16+c, c<11): bond[perm[i]] float2 reads, 4 edges/round
// Bond slot-sums reduced via shfl_xor(32,16) (c preserved), then 11-step
// shfl broadcast into the per-lane f32 dot. Replaces k_bsum entirely.
__global__ __launch_bounds__(256) void k_gather(
    const int* __restrict__ row, const int* __restrict__ perm,
    const uint2* __restrict__ rec8s, const float* __restrict__ bond,
    const float* __restrict__ w_n, const float* __restrict__ pb,
    const float4* __restrict__ xyz, float* __restrict__ out)
{
    const int lane = threadIdx.x & 63;
    const int wid  = (int)((blockIdx.x * blockDim.x + threadIdx.x) >> 6);
    if (wid >= N_NODES) return;
    const int n = __builtin_amdgcn_readfirstlane(wid);

    // per-lane bond-weight columns (f32)
    float wnb[NB];
#pragma unroll
    for (int j = 0; j < NB; ++j) wnb[j] = w_n[(NF + j) * OC + lane];
    const float w0 = w_n[0 * OC + lane];
    const float w1 = w_n[1 * OC + lane];
    const float w2 = w_n[2 * OC + lane];

    const int rs = row[n], re = row[n + 1];
    const float4 xs = xyz[n];
    const float pa = pb[(long)n * OC + lane]
                   - (xs.x * w0 + xs.y * w1 + xs.z * w2);

    const int m = re - rs;
    const uint2* rp = rec8s + rs;
    const int*   pp = perm + rs;

    // bond lane role: slot u = lane>>4 (edge within 4-edge round),
    // channel pair c = lane&15 (active if c < 11; covers channels 2c, 2c+1)
    const int  bu   = lane >> 4;
    const int  bc_i = lane & 15;
    const bool bact = bc_i < 11;

    float acc = 0.f, inv_sum = 0.f;
    float sx = 0.f, sy = 0.f;                 // bond channel-pair partial sums
    int i = 0;

    // ---- 8 edges in flight (2 bond rounds of 4)
    for (; i + 8 <= m; i += 8) {
        uint2 r[8];
#pragma unroll
        for (int u = 0; u < 8; ++u) r[u] = rp[i + u];
        int pe[8];
#pragma unroll
        for (int u = 0; u < 8; ++u)
            pe[u] = __builtin_amdgcn_readfirstlane(clampe(pp[i + u]));
        float pbt[8];
#pragma unroll
        for (int u = 0; u < 8; ++u)
            pbt[u] = pb[(long)(int)r[u].y * OC + lane];
        if (bact) {
            const float2 vA = *(const float2*)(bond + (size_t)pe[bu] * NB + 2 * bc_i);
            const float2 vB = *(const float2*)(bond + (size_t)pe[4 + bu] * NB + 2 * bc_i);
            sx += vA.x + vB.x;
            sy += vA.y + vB.y;
        }
#pragma unroll
        for (int u = 0; u < 8; ++u) {
            const float inv = __uint_as_float(r[u].x);
            acc += inv * pbt[u];
            inv_sum += inv;
        }
    }
    // ---- 4 edges in flight (1 bond round)
    for (; i + 4 <= m; i += 4) {
        uint2 r[4];
#pragma unroll
        for (int u = 0; u < 4; ++u) r[u] = rp[i + u];
        int pe[4];
#pragma unroll
        for (int u = 0; u < 4; ++u)
            pe[u] = __builtin_amdgcn_readfirstlane(clampe(pp[i + u]));
        float pbt[4];
#pragma unroll
        for (int u = 0; u < 4; ++u)
            pbt[u] = pb[(long)(int)r[u].y * OC + lane];
        if (bact) {
            const float2 v = *(const float2*)(bond + (size_t)pe[bu] * NB + 2 * bc_i);
            sx += v.x;
            sy += v.y;
        }
#pragma unroll
        for (int u = 0; u < 4; ++u) {
            const float inv = __uint_as_float(r[u].x);
            acc += inv * pbt[u];
            inv_sum += inv;
        }
    }
    // ---- singles (bond read on slot-0 lanes only)
    for (; i < m; ++i) {
        const uint2 r = rp[i];
        const int pe0 = __builtin_amdgcn_readfirstlane(clampe(pp[i]));
        if (bu == 0 && bact) {
            const float2 v = *(const float2*)(bond + (size_t)pe0 * NB + 2 * bc_i);
            sx += v.x;
            sy += v.y;
        }
        const float inv = __uint_as_float(r.x);
        acc += inv * pb[(long)(int)r.y * OC + lane];
        inv_sum += inv;
    }
    acc += pa * inv_sum;

    // ---- reduce bond slot-sums: orbit {c, c+16, c+32, c+48} -> total on all
    sx += __shfl_xor(sx, 32);  sy += __shfl_xor(sy, 32);
    sx += __shfl_xor(sx, 16);  sy += __shfl_xor(sy, 16);
    // lane j (j<11) now holds channel sums (2j, 2j+1); broadcast + dot
    float bcv = 0.f;
#pragma unroll
    for (int j = 0; j < 11; ++j) {
        const float vx = __shfl(sx, j);
        const float vy = __shfl(sy, j);
        bcv += vx * wnb[2 * j] + vy * wnb[2 * j + 1];
    }

    out[(long)n * OC + lane] += acc + bcv;
}

// ---------------------------------------------------------------------------
extern "C" void kernel_launch(void* const* d_in, const int* in_sizes, int n_in,
                              void* d_out, int out_size, void* d_ws, size_t ws_size,
                              hipStream_t stream) {
    const float* feat = (const float*)d_in[0];
    const float* bond = (const float*)d_in[1];
    const float* w_s  = (const float*)d_in[2];
    const float* w_n  = (const float*)d_in[3];
    const int*   src  = (const int*)d_in[4];
    const int*   dstv = (const int*)d_in[5];
    float* out = (float*)d_out;

    // workspace layout (16B-aligned), ~40.9 MB total. NO aliasing anywhere.
    char* base = (char*)d_ws;
    float*    pb     = (float*)   (base);                 // 25,600,000
    float4*   xyz    = (float4*)  (base + 25600000);      //  1,600,000
    int*      row    = (int*)     (base + 27200000);      //    400,016
    int*      cnt    = (int*)     (base + 27600016);      //    400,000
    int*      rank   = (int*)     (base + 28000016);      //  3,200,000
    int*      bsc    = (int*)     (base + 31200016);      //        560 (pad)
    short*    btw    = (short*)   (base + 31200640);      //     49,152 (dedicated B^T)
    uint2*    rec8s  = (uint2*)   (base + 31249792);      //  6,400,000 (8B/edge, sorted)
    int*      perm   = (int*)     (base + 37649792);      //  3,200,000

    hipMemsetAsync(cnt, 0, N_NODES * sizeof(int), stream);

    k_wprep   <<<48, 256, 0, stream>>>(w_s, w_n, btw);
    k_node_mfma<<<(N_NODES + 63) / 64, 256, 0, stream>>>(feat, btw, out, pb, xyz);
    k_hist    <<<(N_EDGES + 255) / 256, 256, 0, stream>>>(src, cnt, rank);
    k_scan_blk<<<SCAN_BLOCKS, 256, 0, stream>>>(cnt, row, bsc);
    k_scan_top<<<1, 128, 0, stream>>>(bsc, row);
    k_scan_add<<<SCAN_BLOCKS, 256, 0, stream>>>(row, bsc);
    k_perm    <<<(N_EDGES + 255) / 256, 256, 0, stream>>>(src, rank, row, perm);
    k_sortrec <<<(N_EDGES + 255) / 256, 256, 0, stream>>>(perm, src, dstv, xyz,
                                                          rec8s);
    k_gather  <<<(N_NODES * 64 + 255) / 256, 256, 0, stream>>>(row, perm, rec8s,
                                                               bond, w_n, pb,
                                                               xyz, out);
}